// Round 7
// baseline (99.911 us; speedup 1.0000x reference)
//
#include <hip/hip_runtime.h>
#include <hip/hip_bf16.h>
#include <cstddef>

// ---------------- problem dims (hard-coded from reference) ----------------
constexpr int cB=4, cN=2000, cT=50, cF=10, cD=64, cR=8, cK=16, cE=32;
constexpr int NODES = cB*cN;     // 8000
constexpr int N1    = cN+1;      // 2001 (padded table incl. zero row m=0)
constexpr int ROWS2 = cB*N1;     // 8004

#define DEV static __device__ __forceinline__

typedef __attribute__((ext_vector_type(8))) short bf16x8;   // 8 bf16 = 4 VGPR
typedef __attribute__((ext_vector_type(4))) float f32x4;
typedef __attribute__((ext_vector_type(4))) int   i32x4;

DEV float leaky(float x){ return fmaxf(x, 0.2f*x); }
DEV float wsumall(float v){           // butterfly all-reduce over 64 lanes
  v += __shfl_xor(v,32,64); v += __shfl_xor(v,16,64); v += __shfl_xor(v,8,64);
  v += __shfl_xor(v,4,64);  v += __shfl_xor(v,2,64);  v += __shfl_xor(v,1,64);
  return v;
}
DEV unsigned fu(float f){ return __float_as_uint(f); }
DEV float hif(float f){ return __uint_as_float(fu(f) & 0xFFFF0000u); }   // truncate to bf16-in-f32
DEV unsigned rne16(float f){                                             // RNE bf16 bits of f
  unsigned u = fu(f);
  return (u + 0x7FFFu + ((u>>16)&1u)) >> 16;
}
DEV bf16x8 pack4(unsigned a, unsigned b, unsigned c2, unsigned d){
  union { i32x4 i; bf16x8 h; } u;
  u.i = (i32x4){(int)a,(int)b,(int)c2,(int)d};
  return u.h;
}
DEV unsigned PLO(unsigned x, unsigned y){ return __builtin_amdgcn_perm(y, x, 0x05040100u); }
DEV unsigned PHI(unsigned x, unsigned y){ return __builtin_amdgcn_perm(y, x, 0x07060302u); }
// (hi-trunc of f | hi-trunc of rem<<16) in 3 ops: and, sub, perm
DEV unsigned pack_hl3(float f){
  float rem = f - hif(f);
  return PHI(fu(f), fu(rem));
}
DEV f32x4 MF(bf16x8 a, bf16x8 b, f32x4 c){
  return __builtin_amdgcn_mfma_f32_16x16x32_bf16(a, b, c, 0, 0, 0);
}
DEV float bfu(unsigned short u){ return __uint_as_float(((unsigned)u)<<16); }
DEV float ex2(float x){ float r; asm("v_exp_f32 %0, %1" : "=v"(r) : "v"(x)); return r; }

// ====== K1: GRU (MFMA, 2-tile intra-wave pipeline) + fused projection =====
// Block = 256 thr = 4 waves over TWO independent 16-node tiles (A: nb,
// B: nb+16). Wave w owns gate d-slice [16w,16w+16) of both tiles; the R5
// step body runs twice per t (A then B) so B's independent MFMA/VALU issue
// hides A's LDS/MFMA/gate latency inside one wave (no co-resident block
// needed; 250 blocks ~= 1/CU). One lgkm-only barrier per step; X prefetch
// (2 ahead) never drained. log2e folded into U/W/b so gates use native
// v_exp_f32. Epilogue: wave w projects both tiles for r=2w,2w+1, loading
// each proj_W[r] once -> actb bf16 + sng2.
__global__ __launch_bounds__(256, 1) void k_gru(const float* __restrict__ X,
    const float* __restrict__ gW, const float* __restrict__ gU,
    const float* __restrict__ gb, const float* __restrict__ pW,
    const float* __restrict__ pb, const float* __restrict__ sattW,
    float* __restrict__ node, unsigned short* __restrict__ actb,
    float* __restrict__ sng2)
{
  __shared__ unsigned sHA[2][1024];     // [buf][node*64+d] ^ ((node&7)<<2)
  __shared__ unsigned sHB[2][1024];

  const int tid  = threadIdx.x;
  const int lane = tid & 63;
  const int w    = tid >> 6;            // wave 0..3 -> d-slice
  const int c    = lane & 15;
  const int kg   = lane >> 4;
  const int nbA  = (int)blockIdx.x * 32;
  const int nbB  = nbA + 16;
  const int col  = 16*w + c;            // d-channel this lane produces
  const int bbA  = nbA / cN;
  const int bbB  = nbB / cN;

  const float SZ = -1.4426950408889634f;   // -log2(e): z,r gates
  const float SH =  2.8853900817779268f;   // 2*log2(e): h~ gate

  // ---- persistent B fragments (VGPR, shared by both tiles) ----
  bf16x8 BUhi[2][3], BUlo[2][3], BX[3];
  #pragma unroll
  for (int s=0;s<2;++s){
    #pragma unroll
    for (int cls=0; cls<3; ++cls){
      const float sc = (cls==2) ? SH : SZ;
      const int n = cls*64 + col;
      unsigned hi[4], lo[4];
      #pragma unroll
      for (int p=0;p<4;++p){
        float u0 = sc * gU[(s*32 + kg*8 + 2*p    )*192 + n];
        float u1 = sc * gU[(s*32 + kg*8 + 2*p + 1)*192 + n];
        hi[p] = (fu(u0)>>16) | (fu(u1) & 0xFFFF0000u);
        lo[p] = rne16(u0 - hif(u0)) | (rne16(u1 - hif(u1)) << 16);
      }
      BUhi[s][cls] = pack4(hi[0],hi[1],hi[2],hi[3]);
      BUlo[s][cls] = pack4(lo[0],lo[1],lo[2],lo[3]);
    }
  }
  #pragma unroll
  for (int cls=0; cls<3; ++cls){
    const float sc = (cls==2) ? SH : SZ;
    const int n = cls*64 + col;
    unsigned wd[4];
    #pragma unroll
    for (int p=0;p<4;++p){
      int f = kg*4 + p;
      unsigned v = (f < cF) ? rne16(sc * gW[f*192 + n]) : 0u;
      wd[p] = v | (v << 16);            // k=2f (x_hi) and k=2f+1 (x_lo)
    }
    BX[cls] = pack4(wd[0],wd[1],wd[2],wd[3]);
  }

  // ---- scaled biases -> accumulator inits ----
  const float bz  = SZ*(gb[col]      + gb[192+col]);
  const float br  = SZ*(gb[64+col]   + gb[256+col]);
  const float bh0 = SH* gb[128+col];
  const float bh1 = SH* gb[320+col];

  // ---- zero h-tile buffers (buf 0 of each tile) ----
  for (int i2 = tid; i2 < 1024; i2 += 256){ sHA[0][i2] = 0u; sHB[0][i2] = 0u; }
  f32x4 hoA = {0.f,0.f,0.f,0.f}, hoB = {0.f,0.f,0.f,0.f};
  __syncthreads();

  // ---- x prefetch, 2 steps ahead, per tile ----
  float xcA[4], xnA[4], xcB[4], xnB[4];
  const float* XbA = X + (size_t)(nbA + c)*cT*cF;
  const float* XbB = X + (size_t)(nbB + c)*cT*cF;
  {
    #pragma unroll
    for (int p=0;p<4;++p){ int f = 4*kg+p;
      xcA[p] = (f < cF) ? XbA[0*cF + f] : 0.f;
      xnA[p] = (f < cF) ? XbA[1*cF + f] : 0.f;
      xcB[p] = (f < cF) ? XbB[0*cF + f] : 0.f;
      xnB[p] = (f < cF) ? XbB[1*cF + f] : 0.f;
    }
  }

  const unsigned sw  = (unsigned)((c&7)<<2);
  const unsigned rb0 = (unsigned)(c*64 + kg*8);

  for (int t = 0; t < cT; ++t){
    const int tn = (t+2 < cT) ? t+2 : cT-1;
    // ======================= tile A =======================
    {
      bf16x8 xf = pack4(pack_hl3(xcA[0]), pack_hl3(xcA[1]),
                        pack_hl3(xcA[2]), pack_hl3(xcA[3]));
      #pragma unroll
      for (int p=0;p<4;++p) xcA[p] = xnA[p];
      #pragma unroll
      for (int p=0;p<4;++p){ int f = 4*kg+p; xnA[p] = (f < cF) ? XbA[(size_t)tn*cF + f] : 0.f; }

      const unsigned* sr = sHA[t & 1];
      i32x4 qa = *(const i32x4*)(sr + ((rb0 +  0) ^ sw));
      i32x4 qb = *(const i32x4*)(sr + ((rb0 +  4) ^ sw));
      i32x4 qc = *(const i32x4*)(sr + ((rb0 + 32) ^ sw));
      i32x4 qd = *(const i32x4*)(sr + ((rb0 + 36) ^ sw));
      bf16x8 hh0 = pack4(PLO(qa[0],qa[1]), PLO(qa[2],qa[3]), PLO(qb[0],qb[1]), PLO(qb[2],qb[3]));
      bf16x8 hl0 = pack4(PHI(qa[0],qa[1]), PHI(qa[2],qa[3]), PHI(qb[0],qb[1]), PHI(qb[2],qb[3]));
      bf16x8 hh1 = pack4(PLO(qc[0],qc[1]), PLO(qc[2],qc[3]), PLO(qd[0],qd[1]), PLO(qd[2],qd[3]));
      bf16x8 hl1 = pack4(PHI(qc[0],qc[1]), PHI(qc[2],qc[3]), PHI(qd[0],qd[1]), PHI(qd[2],qd[3]));

      f32x4 aZ  = {bz,bz,bz,bz};
      f32x4 aR  = {br,br,br,br};
      f32x4 aHc = {bh1,bh1,bh1,bh1};
      f32x4 aXh = {bh0,bh0,bh0,bh0};
      aZ  = MF(xf, BX[0], aZ);
      aR  = MF(xf, BX[1], aR);
      aXh = MF(xf, BX[2], aXh);
      aZ  = MF(hh0, BUhi[0][0], aZ);  aZ  = MF(hh1, BUhi[1][0], aZ);
      aR  = MF(hh0, BUhi[0][1], aR);  aR  = MF(hh1, BUhi[1][1], aR);
      aHc = MF(hh0, BUhi[0][2], aHc); aHc = MF(hh1, BUhi[1][2], aHc);
      aZ  = MF(hl0, BUhi[0][0], aZ);  aZ  = MF(hl1, BUhi[1][0], aZ);
      aR  = MF(hl0, BUhi[0][1], aR);  aR  = MF(hl1, BUhi[1][1], aR);
      aHc = MF(hl0, BUhi[0][2], aHc); aHc = MF(hl1, BUhi[1][2], aHc);
      aZ  = MF(hh0, BUlo[0][0], aZ);  aZ  = MF(hh1, BUlo[1][0], aZ);
      aR  = MF(hh0, BUlo[0][1], aR);  aR  = MF(hh1, BUlo[1][1], aR);
      aHc = MF(hh0, BUlo[0][2], aHc); aHc = MF(hh1, BUlo[1][2], aHc);

      unsigned* swr = sHA[(t & 1) ^ 1];
      #pragma unroll
      for (int reg=0; reg<4; ++reg){
        float z   = __builtin_amdgcn_rcpf(1.0f + ex2(aZ[reg]));
        float r   = __builtin_amdgcn_rcpf(1.0f + ex2(aR[reg]));
        float phv = __builtin_fmaf(r, aHc[reg], aXh[reg]);
        float th  = __builtin_fmaf(-2.0f, __builtin_amdgcn_rcpf(ex2(phv) + 1.0f), 1.0f);
        float hn  = __builtin_fmaf(z, hoA[reg]-th, th);
        hoA[reg] = hn;
        int nodei = kg*4 + reg;
        swr[((unsigned)(nodei*64 + col)) ^ ((unsigned)((nodei&7)<<2))] = pack_hl3(hn);
      }
    }
    // ======================= tile B =======================
    {
      bf16x8 xf = pack4(pack_hl3(xcB[0]), pack_hl3(xcB[1]),
                        pack_hl3(xcB[2]), pack_hl3(xcB[3]));
      #pragma unroll
      for (int p=0;p<4;++p) xcB[p] = xnB[p];
      #pragma unroll
      for (int p=0;p<4;++p){ int f = 4*kg+p; xnB[p] = (f < cF) ? XbB[(size_t)tn*cF + f] : 0.f; }

      const unsigned* sr = sHB[t & 1];
      i32x4 qa = *(const i32x4*)(sr + ((rb0 +  0) ^ sw));
      i32x4 qb = *(const i32x4*)(sr + ((rb0 +  4) ^ sw));
      i32x4 qc = *(const i32x4*)(sr + ((rb0 + 32) ^ sw));
      i32x4 qd = *(const i32x4*)(sr + ((rb0 + 36) ^ sw));
      bf16x8 hh0 = pack4(PLO(qa[0],qa[1]), PLO(qa[2],qa[3]), PLO(qb[0],qb[1]), PLO(qb[2],qb[3]));
      bf16x8 hl0 = pack4(PHI(qa[0],qa[1]), PHI(qa[2],qa[3]), PHI(qb[0],qb[1]), PHI(qb[2],qb[3]));
      bf16x8 hh1 = pack4(PLO(qc[0],qc[1]), PLO(qc[2],qc[3]), PLO(qd[0],qd[1]), PLO(qd[2],qd[3]));
      bf16x8 hl1 = pack4(PHI(qc[0],qc[1]), PHI(qc[2],qc[3]), PHI(qd[0],qd[1]), PHI(qd[2],qd[3]));

      f32x4 aZ  = {bz,bz,bz,bz};
      f32x4 aR  = {br,br,br,br};
      f32x4 aHc = {bh1,bh1,bh1,bh1};
      f32x4 aXh = {bh0,bh0,bh0,bh0};
      aZ  = MF(xf, BX[0], aZ);
      aR  = MF(xf, BX[1], aR);
      aXh = MF(xf, BX[2], aXh);
      aZ  = MF(hh0, BUhi[0][0], aZ);  aZ  = MF(hh1, BUhi[1][0], aZ);
      aR  = MF(hh0, BUhi[0][1], aR);  aR  = MF(hh1, BUhi[1][1], aR);
      aHc = MF(hh0, BUhi[0][2], aHc); aHc = MF(hh1, BUhi[1][2], aHc);
      aZ  = MF(hl0, BUhi[0][0], aZ);  aZ  = MF(hl1, BUhi[1][0], aZ);
      aR  = MF(hl0, BUhi[0][1], aR);  aR  = MF(hl1, BUhi[1][1], aR);
      aHc = MF(hl0, BUhi[0][2], aHc); aHc = MF(hl1, BUhi[1][2], aHc);
      aZ  = MF(hh0, BUlo[0][0], aZ);  aZ  = MF(hh1, BUlo[1][0], aZ);
      aR  = MF(hh0, BUlo[0][1], aR);  aR  = MF(hh1, BUlo[1][1], aR);
      aHc = MF(hh0, BUlo[0][2], aHc); aHc = MF(hh1, BUlo[1][2], aHc);

      unsigned* swr = sHB[(t & 1) ^ 1];
      #pragma unroll
      for (int reg=0; reg<4; ++reg){
        float z   = __builtin_amdgcn_rcpf(1.0f + ex2(aZ[reg]));
        float r   = __builtin_amdgcn_rcpf(1.0f + ex2(aR[reg]));
        float phv = __builtin_fmaf(r, aHc[reg], aXh[reg]);
        float th  = __builtin_fmaf(-2.0f, __builtin_amdgcn_rcpf(ex2(phv) + 1.0f), 1.0f);
        float hn  = __builtin_fmaf(z, hoB[reg]-th, th);
        hoB[reg] = hn;
        int nodei = kg*4 + reg;
        swr[((unsigned)(nodei*64 + col)) ^ ((unsigned)((nodei&7)<<2))] = pack_hl3(hn);
      }
    }
    // LDS visible, X prefetch stays in flight
    asm volatile("s_waitcnt lgkmcnt(0)" ::: "memory");
    __builtin_amdgcn_s_barrier();
  }

  // ---- write out h (fp32) for k_attn ----
  #pragma unroll
  for (int reg=0; reg<4; ++reg){
    node[(size_t)(nbA + kg*4 + reg)*cD + col] = hoA[reg];
    node[(size_t)(nbB + kg*4 + reg)*cD + col] = hoB[reg];
  }

  // ================= fused projection epilogue =================
  // final h (hi|lo) is in sHA[0]/sHB[0] (t=49 wrote buf 0; barrier passed)
  {
    const unsigned* srA = &sHA[0][0];
    i32x4 qa = *(const i32x4*)(srA + ((rb0 +  0) ^ sw));
    i32x4 qb = *(const i32x4*)(srA + ((rb0 +  4) ^ sw));
    i32x4 qc = *(const i32x4*)(srA + ((rb0 + 32) ^ sw));
    i32x4 qd = *(const i32x4*)(srA + ((rb0 + 36) ^ sw));
    bf16x8 hh0A = pack4(PLO(qa[0],qa[1]), PLO(qa[2],qa[3]), PLO(qb[0],qb[1]), PLO(qb[2],qb[3]));
    bf16x8 hl0A = pack4(PHI(qa[0],qa[1]), PHI(qa[2],qa[3]), PHI(qb[0],qb[1]), PHI(qb[2],qb[3]));
    bf16x8 hh1A = pack4(PLO(qc[0],qc[1]), PLO(qc[2],qc[3]), PLO(qd[0],qd[1]), PLO(qd[2],qd[3]));
    bf16x8 hl1A = pack4(PHI(qc[0],qc[1]), PHI(qc[2],qc[3]), PHI(qd[0],qd[1]), PHI(qd[2],qd[3]));
    const unsigned* srB = &sHB[0][0];
    qa = *(const i32x4*)(srB + ((rb0 +  0) ^ sw));
    qb = *(const i32x4*)(srB + ((rb0 +  4) ^ sw));
    qc = *(const i32x4*)(srB + ((rb0 + 32) ^ sw));
    qd = *(const i32x4*)(srB + ((rb0 + 36) ^ sw));
    bf16x8 hh0B = pack4(PLO(qa[0],qa[1]), PLO(qa[2],qa[3]), PLO(qb[0],qb[1]), PLO(qb[2],qb[3]));
    bf16x8 hl0B = pack4(PHI(qa[0],qa[1]), PHI(qa[2],qa[3]), PHI(qb[0],qb[1]), PHI(qb[2],qb[3]));
    bf16x8 hh1B = pack4(PLO(qc[0],qc[1]), PLO(qc[2],qc[3]), PLO(qd[0],qd[1]), PLO(qd[2],qd[3]));
    bf16x8 hl1B = pack4(PHI(qc[0],qc[1]), PHI(qc[2],qc[3]), PHI(qd[0],qd[1]), PHI(qd[2],qd[3]));

    const int qbaseA = nbA + bbA + 1;     // padded-table row of node nbA
    const int qbaseB = nbB + bbB + 1;
    #pragma unroll
    for (int rr=0; rr<2; ++rr){
      const int r = 2*w + rr;
      const float* Pr = pW + (size_t)r*cD*cD;
      bf16x8 PB[4][2];
      float pbv[4], wnv[4];
      #pragma unroll
      for (int cb=0; cb<4; ++cb){
        const int e = 16*cb + c;
        #pragma unroll
        for (int s2=0;s2<2;++s2){
          unsigned wd[4];
          #pragma unroll
          for (int p=0;p<4;++p){
            int k0 = s2*32 + kg*8 + 2*p;
            wd[p] = rne16(Pr[(size_t)k0*cD + e]) | (rne16(Pr[(size_t)(k0+1)*cD + e]) << 16);
          }
          PB[cb][s2] = pack4(wd[0],wd[1],wd[2],wd[3]);
        }
        pbv[cb] = pb[r*cD + e];
        wnv[cb] = sattW[r*(2*cD+cE) + cD + e];
      }
      // tile A
      {
        float sp[4] = {0.f,0.f,0.f,0.f};
        #pragma unroll
        for (int cb=0; cb<4; ++cb){
          f32x4 acc = {pbv[cb],pbv[cb],pbv[cb],pbv[cb]};
          acc = MF(hh0A, PB[cb][0], acc); acc = MF(hh1A, PB[cb][1], acc);
          acc = MF(hl0A, PB[cb][0], acc); acc = MF(hl1A, PB[cb][1], acc);
          #pragma unroll
          for (int reg=0; reg<4; ++reg){
            float o = leaky(acc[reg]);
            int qrow = qbaseA + kg*4 + reg;
            actb[((size_t)r*ROWS2 + qrow)*cD + 16*cb + c] = (unsigned short)rne16(o);
            sp[reg] = __builtin_fmaf(o, wnv[cb], sp[reg]);
          }
        }
        #pragma unroll
        for (int reg=0; reg<4; ++reg){
          float s2 = sp[reg];
          s2 += __shfl_xor(s2,1,64); s2 += __shfl_xor(s2,2,64);
          s2 += __shfl_xor(s2,4,64); s2 += __shfl_xor(s2,8,64);
          if (c == 0) sng2[(size_t)r*ROWS2 + qbaseA + kg*4 + reg] = s2;
        }
      }
      // tile B
      {
        float sp[4] = {0.f,0.f,0.f,0.f};
        #pragma unroll
        for (int cb=0; cb<4; ++cb){
          f32x4 acc = {pbv[cb],pbv[cb],pbv[cb],pbv[cb]};
          acc = MF(hh0B, PB[cb][0], acc); acc = MF(hh1B, PB[cb][1], acc);
          acc = MF(hl0B, PB[cb][0], acc); acc = MF(hl1B, PB[cb][1], acc);
          #pragma unroll
          for (int reg=0; reg<4; ++reg){
            float o = leaky(acc[reg]);
            int qrow = qbaseB + kg*4 + reg;
            actb[((size_t)r*ROWS2 + qrow)*cD + 16*cb + c] = (unsigned short)rne16(o);
            sp[reg] = __builtin_fmaf(o, wnv[cb], sp[reg]);
          }
        }
        #pragma unroll
        for (int reg=0; reg<4; ++reg){
          float s2 = sp[reg];
          s2 += __shfl_xor(s2,1,64); s2 += __shfl_xor(s2,2,64);
          s2 += __shfl_xor(s2,4,64); s2 += __shfl_xor(s2,8,64);
          if (c == 0) sng2[(size_t)r*ROWS2 + qbaseB + kg*4 + reg] = s2;
        }
      }
    }
  }

  // ---- blocks whose tile starts a batch write the m=0 (zero-input) rows ----
  if ((nbA % cN) == 0){
    #pragma unroll
    for (int rr=0; rr<2; ++rr){
      const int r = 2*w + rr;
      float v0 = leaky(pb[r*cD + lane]);
      float wv = sattW[r*(2*cD+cE) + cD + lane];
      actb[((size_t)r*ROWS2 + (size_t)bbA*N1)*cD + lane] = (unsigned short)rne16(v0);
      float s2 = wsumall(v0 * wv);
      if (lane == 0) sng2[(size_t)r*ROWS2 + (size_t)bbA*N1] = s2;
    }
  }
  if ((nbB % cN) == 0){
    #pragma unroll
    for (int rr=0; rr<2; ++rr){
      const int r = 2*w + rr;
      float v0 = leaky(pb[r*cD + lane]);
      float wv = sattW[r*(2*cD+cE) + cD + lane];
      actb[((size_t)r*ROWS2 + (size_t)bbB*N1)*cD + lane] = (unsigned short)rne16(v0);
      float s2 = wsumall(v0 * wv);
      if (lane == 0) sng2[(size_t)r*ROWS2 + (size_t)bbB*N1] = s2;
    }
  }
}

// ============ K3: fused attention + head (+ per-r scalars), 1 wave/(b,n) ==
__global__ __launch_bounds__(256) void k_attn(const float* __restrict__ node,
    const int* __restrict__ nbrs, const float* __restrict__ sattW,
    const float* __restrict__ sattb, const float* __restrict__ rattW,
    const float* __restrict__ rattb, const float* __restrict__ predW,
    const float* __restrict__ predb, const float* __restrict__ relemb,
    const unsigned short* __restrict__ actb, const float* __restrict__ sng2,
    float* __restrict__ out)
{
  __shared__ float sSA[cR][cD];        // w_cur rows
  __shared__ float sSrel[cR], sRremb[cR];
  __shared__ float sAtt[4][cR][cK];
  __shared__ int   sOff[4][cR][cK];
  const int tid = threadIdx.x;
  for (int i=tid; i<cR*cD; i+=256) sSA[i>>6][i&63] = sattW[(i>>6)*(2*cD+cE) + (i&63)];
  if (tid < 64){                       // fold old k_prep: srel, rremb
    int r = tid >> 3, j0 = (tid & 7)*4;
    float a = 0.f, b2 = 0.f;
    #pragma unroll
    for (int j=0;j<4;++j){
      float re = relemb[r*cE + j0 + j];
      a  += re * sattW[r*(2*cD+cE) + 2*cD + j0 + j];
      b2 += re * rattW[2*cD + j0 + j];
    }
    a  += __shfl_xor(a,1,64);  a  += __shfl_xor(a,2,64);  a  += __shfl_xor(a,4,64);
    b2 += __shfl_xor(b2,1,64); b2 += __shfl_xor(b2,2,64); b2 += __shfl_xor(b2,4,64);
    if ((tid & 7) == 0){ sSrel[r] = a + sattb[r]; sRremb[r] = b2; }
  }
  __syncthreads();

  const int wave = tid >> 6, lane = tid & 63;
  const int gn = (int)blockIdx.x*4 + wave;          // 0..7999
  const int b = __builtin_amdgcn_readfirstlane(gn / cN);
  const int n = __builtin_amdgcn_readfirstlane(gn % cN);

  const float cur = node[(size_t)gn*cD + lane];

  float scr[8];
  #pragma unroll
  for (int r=0; r<8; ++r) scr[r] = wsumall(cur * sSA[r][lane]);

  const int g = lane >> 4, k = lane & 15;
  #pragma unroll
  for (int half=0; half<2; ++half){
    int r = half*4 + g;
    float sc0 = half==0 ? (g==0?scr[0]:g==1?scr[1]:g==2?scr[2]:scr[3])
                        : (g==0?scr[4]:g==1?scr[5]:g==2?scr[6]:scr[7]);
    int idx = nbrs[(((size_t)b*cR + r)*cN + n)*cK + k];
    int o = r*ROWS2 + b*N1 + idx;
    float sv = sng2[o];
    float sc = leaky(sc0 + sv + sSrel[r]);
    if (idx == 0) sc -= 1e9f;
    float mx = sc;
    mx = fmaxf(mx, __shfl_xor(mx,1,64)); mx = fmaxf(mx, __shfl_xor(mx,2,64));
    mx = fmaxf(mx, __shfl_xor(mx,4,64)); mx = fmaxf(mx, __shfl_xor(mx,8,64));
    float ex = __expf(sc - mx);
    float sm = ex;
    sm += __shfl_xor(sm,1,64); sm += __shfl_xor(sm,2,64);
    sm += __shfl_xor(sm,4,64); sm += __shfl_xor(sm,8,64);
    sAtt[wave][r][k] = ex/sm;
    sOff[wave][r][k] = o;
  }
  __syncthreads();

  float facc[8];
  #pragma unroll
  for (int r=0; r<8; ++r){
    float a0=0.f, a1=0.f;
    #pragma unroll
    for (int kk=0; kk<cK; kk+=2){
      float w0 = sAtt[wave][r][kk],   w1 = sAtt[wave][r][kk+1];
      int   o0 = sOff[wave][r][kk],   o1 = sOff[wave][r][kk+1];
      a0 += w0 * bfu(actb[(size_t)o0*cD + lane]);
      a1 += w1 * bfu(actb[(size_t)o1*cD + lane]);
    }
    facc[r] = a0 + a1;
  }

  const float rcur = rattW[lane], rrep = rattW[cD + lane];
  const float rb   = rattb[0];
  const float c0 = wsumall(cur * rcur);
  float rs[8];
  #pragma unroll
  for (int r=0; r<8; ++r) rs[r] = leaky(c0 + wsumall(facc[r]*rrep) + sRremb[r] + rb);
  float mx = rs[0];
  #pragma unroll
  for (int r=1; r<8; ++r) mx = fmaxf(mx, rs[r]);
  float es = 0.f; float ratt[8];
  #pragma unroll
  for (int r=0; r<8; ++r){ ratt[r] = __expf(rs[r]-mx); es += ratt[r]; }
  float inv = 1.f/es;
  float agg = 0.f;
  #pragma unroll
  for (int r=0; r<8; ++r) agg += (ratt[r]*inv) * facc[r];
  const float upd = cur + agg;

  float l0 = wsumall(upd * predW[lane*3 + 0]);
  float l1 = wsumall(upd * predW[lane*3 + 1]);
  float l2 = wsumall(upd * predW[lane*3 + 2]);
  if (lane == 0){
    l0 += predb[0]; l1 += predb[1]; l2 += predb[2];
    float m2 = fmaxf(l0, fmaxf(l1, l2));
    float e0 = __expf(l0-m2), e1 = __expf(l1-m2), e2 = __expf(l2-m2);
    float is = 1.f/(e0+e1+e2);
    out[(size_t)gn*3+0] = e0*is;
    out[(size_t)gn*3+1] = e1*is;
    out[(size_t)gn*3+2] = e2*is;
  }
}

// ================================ launch =================================
extern "C" void kernel_launch(void* const* d_in, const int* in_sizes, int n_in,
                              void* d_out, int out_size, void* d_ws, size_t ws_size,
                              hipStream_t stream)
{
  const float* X      = (const float*)d_in[0];
  const int*   nbrs   = (const int*)  d_in[1];
  const float* gW     = (const float*)d_in[2];
  const float* gU     = (const float*)d_in[3];
  const float* gb     = (const float*)d_in[4];
  const float* relemb = (const float*)d_in[5];
  const float* pW     = (const float*)d_in[6];
  const float* pb     = (const float*)d_in[7];
  const float* sattW  = (const float*)d_in[8];
  const float* sattb  = (const float*)d_in[9];
  const float* rattW  = (const float*)d_in[10];
  const float* rattb  = (const float*)d_in[11];
  const float* predW  = (const float*)d_in[12];
  const float* predb  = (const float*)d_in[13];
  float* out = (float*)d_out;

  // workspace: node fp32 | act bf16 (r-major) | sng fp32
  float*          node  = (float*)d_ws;                                 // NODES*cD
  unsigned short* actb  = (unsigned short*)(node + (size_t)NODES*cD);   // cR*ROWS2*cD bf16
  float*          sng2  = (float*)(actb + (size_t)cR*ROWS2*cD);         // cR*ROWS2

  k_gru <<<NODES/32, 256, 0, stream>>>(X, gW, gU, gb, pW, pb, sattW,
                                       node, actb, sng2);
  k_attn<<<NODES/4, 256, 0, stream>>>(node, nbrs, sattW, sattb, rattW, rattb,
                                      predW, predb, relemb, actb, sng2, out);
}

// Round 8
// 81.030 us; speedup vs baseline: 1.2330x; 1.2330x over previous
//
#include <hip/hip_runtime.h>
#include <hip/hip_bf16.h>
#include <cstddef>
#include <cstring>

// ---------------- problem dims (hard-coded from reference) ----------------
constexpr int cB=4, cN=2000, cT=50, cF=10, cD=64, cR=8, cK=16, cE=32;
constexpr int NODES = cB*cN;     // 8000
constexpr int N1    = cN+1;      // 2001 (padded table incl. zero row m=0)
constexpr int ROWS2 = cB*N1;     // 8004

#define DEV static __device__ __forceinline__

typedef __attribute__((ext_vector_type(8))) short    bf16x8;
typedef __attribute__((ext_vector_type(8))) _Float16 f16x8;   // 8 f16 = 4 VGPR
typedef __attribute__((ext_vector_type(4))) float    f32x4;
typedef __attribute__((ext_vector_type(4))) int      i32x4;

DEV float leaky(float x){ return fmaxf(x, 0.2f*x); }
DEV float wsumall(float v){           // butterfly all-reduce over 64 lanes
  v += __shfl_xor(v,32,64); v += __shfl_xor(v,16,64); v += __shfl_xor(v,8,64);
  v += __shfl_xor(v,4,64);  v += __shfl_xor(v,2,64);  v += __shfl_xor(v,1,64);
  return v;
}
DEV unsigned fu(float f){ return __float_as_uint(f); }
DEV unsigned rne16(float f){                      // RNE bf16 bits of f
  unsigned u = fu(f);
  return (u + 0x7FFFu + ((u>>16)&1u)) >> 16;
}
DEV unsigned f16b(float f){                       // f32 -> f16 bits (RNE), zero-extended
  _Float16 h = (_Float16)f;
  unsigned short u; __builtin_memcpy(&u, &h, 2);
  return (unsigned)u;
}
DEV f16x8 packh(unsigned a, unsigned b, unsigned c2, unsigned d){
  union { i32x4 i; f16x8 h; } u;
  u.i = (i32x4){(int)a,(int)b,(int)c2,(int)d};
  return u.h;
}
DEV f16x8 asf16(i32x4 v){
  union { i32x4 i; f16x8 h; } u; u.i = v; return u.h;
}
DEV f32x4 MF16(f16x8 a, f16x8 b, f32x4 c){
  return __builtin_amdgcn_mfma_f32_16x16x32_f16(a, b, c, 0, 0, 0);
}
DEV float bfu(unsigned short u){ return __uint_as_float(((unsigned)u)<<16); }
DEV float ex2(float x){ float r; asm("v_exp_f32 %0, %1" : "=v"(r) : "v"(x)); return r; }

// ========= K1: GRU (MFMA f16, R5 structure) + fused projection ============
// Block = 256 thr = 4 waves over 16 nodes; wave w owns gate d-slice
// [16w,16w+16). Native f16 MFMA (no hi/lo split): 9 MFMA/step/wave, chain
// depth 3. h crosses steps as raw f16 in a double-buffered XOR-swizzled LDS
// tile (ds_write_b16 / 2x ds_read_b128, zero lane-perms). Bias enters via a
// constant-1.0 x-slot (f=10) so gate accumulators start from one persistent
// zero quad. lgkm-only barrier per step; X prefetch (2 ahead) never drained.
// log2e folded into U/W/bias: gates use native v_exp_f32 (exp2).
// Epilogue: wave w projects the 16 nodes for r=2w,2w+1 (8 MFMA each).
__global__ __launch_bounds__(256, 2) void k_gru(const float* __restrict__ X,
    const float* __restrict__ gW, const float* __restrict__ gU,
    const float* __restrict__ gb, const float* __restrict__ pW,
    const float* __restrict__ pb, const float* __restrict__ sattW,
    float* __restrict__ node, unsigned short* __restrict__ actb,
    float* __restrict__ sng2)
{
  __shared__ unsigned sF[2][512];   // [buf][(node*32 + d/2) ^ ((node&7)<<2)] : f16 pair

  const int tid  = threadIdx.x;
  const int lane = tid & 63;
  const int w    = tid >> 6;            // wave 0..3 -> d-slice / r-pair
  const int c    = lane & 15;
  const int kg   = lane >> 4;
  const int nb   = (int)blockIdx.x * 16;
  const int col  = 16*w + c;            // d-channel this lane produces
  const int bb   = nb / cN;             // batch (block-uniform)

  const float SZ = -1.4426950408889634f;   // -log2(e): z,r gates
  const float SH =  2.8853900817779268f;   // 2*log2(e): h~ gate

  // ---- persistent B fragments (VGPR): U f16, per K-half; W f16 k=2f slots --
  f16x8 Uf[2][3];
  #pragma unroll
  for (int s=0;s<2;++s){
    #pragma unroll
    for (int cls=0; cls<3; ++cls){
      const float sc = (cls==2) ? SH : SZ;
      const int n = cls*64 + col;
      unsigned wd[4];
      #pragma unroll
      for (int p=0;p<4;++p){
        int d0 = s*32 + kg*8 + 2*p;
        wd[p] = f16b(sc*gU[d0*192 + n]) | (f16b(sc*gU[(d0+1)*192 + n]) << 16);
      }
      Uf[s][cls] = packh(wd[0],wd[1],wd[2],wd[3]);
    }
  }
  // gate biases (b0+b1 for z/r; bh0 rides x-side; bh1 stays in aHc init)
  const float bzt = SZ*(gb[col] + gb[192+col]);
  const float brt = SZ*(gb[64+col] + gb[256+col]);
  const float bh0 = SH* gb[128+col];
  const float bh1 = SH* gb[320+col];
  f16x8 BXf[3];
  #pragma unroll
  for (int cls=0; cls<3; ++cls){
    const float sc = (cls==2) ? SH : SZ;
    const float bv = (cls==0) ? bzt : (cls==1 ? brt : bh0);
    const int n = cls*64 + col;
    unsigned wd[4];
    #pragma unroll
    for (int p=0;p<4;++p){
      int f = kg*4 + p;
      unsigned v = (f < cF) ? f16b(sc*gW[f*192 + n]) : ((f == cF) ? f16b(bv) : 0u);
      wd[p] = v;                      // hi16 = 0 (odd k-slots multiply zero)
    }
    BXf[cls] = packh(wd[0],wd[1],wd[2],wd[3]);
  }

  // ---- zero h-tile buffer 0 ----
  for (int i2 = tid; i2 < 512; i2 += 256) sF[0][i2] = 0u;
  f32x4 ho = {0.f,0.f,0.f,0.f};
  __syncthreads();

  // ---- x prefetch, 2 steps ahead; f==10 slot carries constant 1.0 (bias) ----
  float xc[4], xn[4];
  const float* Xb = X + (size_t)(nb + c)*cT*cF;
  #pragma unroll
  for (int p=0;p<4;++p){
    int f = 4*kg+p;
    float fill = (f == cF) ? 1.0f : 0.0f;
    xc[p] = (f < cF) ? Xb[0*cF + f] : fill;
    xn[p] = (f < cF) ? Xb[1*cF + f] : fill;
  }

  // ---- hoisted LDS offsets ----
  const unsigned sw2   = (unsigned)((c&7)<<2);
  const unsigned base0 = ((unsigned)(c*32 + kg*4))      ^ sw2;   // d 0..31
  const unsigned base1 = ((unsigned)(c*32 + 16 + kg*4)) ^ sw2;   // d 32..63
  unsigned hws[4];
  #pragma unroll
  for (int reg=0; reg<4; ++reg){
    int nodei = kg*4 + reg;
    hws[reg] = (((unsigned)(nodei*32 + (col>>1))) ^ ((unsigned)((nodei&7)<<2)))*2
               + (unsigned)(col&1);
  }
  const f32x4 zq = {0.f,0.f,0.f,0.f};

  for (int t = 0; t < cT; ++t){
    // ---- x A-fragment (f16 in lo16 of each dword) ----
    f16x8 xf = packh(f16b(xc[0]), f16b(xc[1]), f16b(xc[2]), f16b(xc[3]));
    #pragma unroll
    for (int p=0;p<4;++p) xc[p] = xn[p];
    {
      int tn = (t+2 < cT) ? t+2 : cT-1;
      #pragma unroll
      for (int p=0;p<4;++p){
        int f = 4*kg+p;
        float fill = (f == cF) ? 1.0f : 0.0f;
        xn[p] = (f < cF) ? Xb[(size_t)tn*cF + f] : fill;
      }
    }

    // ---- h A-fragments (raw f16, no perms) ----
    const unsigned* sr = sF[t & 1];
    i32x4 q0 = *(const i32x4*)(sr + base0);
    i32x4 q1 = *(const i32x4*)(sr + base1);
    f16x8 ha = asf16(q0), hb = asf16(q1);

    // ---- MFMA: 9 per wave, chains depth<=3 ----
    f32x4 aZ  = MF16(xf, BXf[0], zq);
    f32x4 aR  = MF16(xf, BXf[1], zq);
    f32x4 aXh = MF16(xf, BXf[2], zq);
    f32x4 aHc = {bh1,bh1,bh1,bh1};
    aZ  = MF16(ha, Uf[0][0], aZ);  aZ  = MF16(hb, Uf[1][0], aZ);
    aR  = MF16(ha, Uf[0][1], aR);  aR  = MF16(hb, Uf[1][1], aR);
    aHc = MF16(ha, Uf[0][2], aHc); aHc = MF16(hb, Uf[1][2], aHc);

    // ---- gates (fp32) -> h as f16 ds_write_b16 (hoisted swizzled addrs) ----
    unsigned short* swr = (unsigned short*)sF[(t & 1) ^ 1];
    #pragma unroll
    for (int reg=0; reg<4; ++reg){
      float z   = __builtin_amdgcn_rcpf(1.0f + ex2(aZ[reg]));
      float r   = __builtin_amdgcn_rcpf(1.0f + ex2(aR[reg]));
      float phv = __builtin_fmaf(r, aHc[reg], aXh[reg]);
      float th  = __builtin_fmaf(-2.0f, __builtin_amdgcn_rcpf(ex2(phv) + 1.0f), 1.0f);
      float hn  = __builtin_fmaf(z, ho[reg]-th, th);
      ho[reg] = hn;
      swr[hws[reg]] = (unsigned short)f16b(hn);
    }
    // LDS visible, X prefetch stays in flight
    asm volatile("s_waitcnt lgkmcnt(0)" ::: "memory");
    __builtin_amdgcn_s_barrier();
  }

  // ---- write out h (fp32) for k_attn ----
  #pragma unroll
  for (int reg=0; reg<4; ++reg)
    node[(size_t)(nb + kg*4 + reg)*cD + col] = ho[reg];

  // ================= fused projection epilogue (f16) =================
  // final h is in sF[0] (t=49 wrote buf 0; barrier passed)
  {
    const unsigned* sr = &sF[0][0];
    i32x4 q0 = *(const i32x4*)(sr + base0);
    i32x4 q1 = *(const i32x4*)(sr + base1);
    f16x8 ha = asf16(q0), hb = asf16(q1);

    const int qbase = nb + bb + 1;        // padded-table row of node nb
    #pragma unroll
    for (int rr=0; rr<2; ++rr){
      const int r = 2*w + rr;
      const float* Pr = pW + (size_t)r*cD*cD;
      f16x8 PB[4][2];
      float pbv[4], wnv[4];
      #pragma unroll
      for (int cb=0; cb<4; ++cb){
        const int e = 16*cb + c;
        #pragma unroll
        for (int s2=0;s2<2;++s2){
          unsigned wd[4];
          #pragma unroll
          for (int p=0;p<4;++p){
            int d0 = s2*32 + kg*8 + 2*p;
            wd[p] = f16b(Pr[(size_t)d0*cD + e]) | (f16b(Pr[(size_t)(d0+1)*cD + e]) << 16);
          }
          PB[cb][s2] = packh(wd[0],wd[1],wd[2],wd[3]);
        }
        pbv[cb] = pb[r*cD + e];
        wnv[cb] = sattW[r*(2*cD+cE) + cD + e];
      }
      float sp[4] = {0.f,0.f,0.f,0.f};
      #pragma unroll
      for (int cb=0; cb<4; ++cb){
        f32x4 acc = {pbv[cb],pbv[cb],pbv[cb],pbv[cb]};
        acc = MF16(ha, PB[cb][0], acc);
        acc = MF16(hb, PB[cb][1], acc);
        #pragma unroll
        for (int reg=0; reg<4; ++reg){
          float o = leaky(acc[reg]);
          int qrow = qbase + kg*4 + reg;
          actb[((size_t)r*ROWS2 + qrow)*cD + 16*cb + c] = (unsigned short)rne16(o);
          sp[reg] = __builtin_fmaf(o, wnv[cb], sp[reg]);
        }
      }
      #pragma unroll
      for (int reg=0; reg<4; ++reg){
        float s2 = sp[reg];
        s2 += __shfl_xor(s2,1,64); s2 += __shfl_xor(s2,2,64);
        s2 += __shfl_xor(s2,4,64); s2 += __shfl_xor(s2,8,64);
        if (c == 0) sng2[(size_t)r*ROWS2 + qbase + kg*4 + reg] = s2;
      }
    }
  }

  // ---- 4 designated blocks write the m=0 (zero-input) rows ----
  if ((blockIdx.x % (cN/16)) == 0){
    #pragma unroll
    for (int rr=0; rr<2; ++rr){
      const int r = 2*w + rr;
      float v0 = leaky(pb[r*cD + lane]);
      float wv = sattW[r*(2*cD+cE) + cD + lane];
      actb[((size_t)r*ROWS2 + (size_t)bb*N1)*cD + lane] = (unsigned short)rne16(v0);
      float s2 = wsumall(v0 * wv);
      if (lane == 0) sng2[(size_t)r*ROWS2 + (size_t)bb*N1] = s2;
    }
  }
}

// ============ K3: fused attention + head (+ per-r scalars), 1 wave/(b,n) ==
__global__ __launch_bounds__(256) void k_attn(const float* __restrict__ node,
    const int* __restrict__ nbrs, const float* __restrict__ sattW,
    const float* __restrict__ sattb, const float* __restrict__ rattW,
    const float* __restrict__ rattb, const float* __restrict__ predW,
    const float* __restrict__ predb, const float* __restrict__ relemb,
    const unsigned short* __restrict__ actb, const float* __restrict__ sng2,
    float* __restrict__ out)
{
  __shared__ float sSA[cR][cD];        // w_cur rows
  __shared__ float sSrel[cR], sRremb[cR];
  __shared__ float sAtt[4][cR][cK];
  __shared__ int   sOff[4][cR][cK];
  const int tid = threadIdx.x;
  for (int i=tid; i<cR*cD; i+=256) sSA[i>>6][i&63] = sattW[(i>>6)*(2*cD+cE) + (i&63)];
  if (tid < 64){                       // fold old k_prep: srel, rremb
    int r = tid >> 3, j0 = (tid & 7)*4;
    float a = 0.f, b2 = 0.f;
    #pragma unroll
    for (int j=0;j<4;++j){
      float re = relemb[r*cE + j0 + j];
      a  += re * sattW[r*(2*cD+cE) + 2*cD + j0 + j];
      b2 += re * rattW[2*cD + j0 + j];
    }
    a  += __shfl_xor(a,1,64);  a  += __shfl_xor(a,2,64);  a  += __shfl_xor(a,4,64);
    b2 += __shfl_xor(b2,1,64); b2 += __shfl_xor(b2,2,64); b2 += __shfl_xor(b2,4,64);
    if ((tid & 7) == 0){ sSrel[r] = a + sattb[r]; sRremb[r] = b2; }
  }
  __syncthreads();

  const int wave = tid >> 6, lane = tid & 63;
  const int gn = (int)blockIdx.x*4 + wave;          // 0..7999
  const int b = __builtin_amdgcn_readfirstlane(gn / cN);
  const int n = __builtin_amdgcn_readfirstlane(gn % cN);

  const float cur = node[(size_t)gn*cD + lane];

  float scr[8];
  #pragma unroll
  for (int r=0; r<8; ++r) scr[r] = wsumall(cur * sSA[r][lane]);

  const int g = lane >> 4, k = lane & 15;
  #pragma unroll
  for (int half=0; half<2; ++half){
    int r = half*4 + g;
    float sc0 = half==0 ? (g==0?scr[0]:g==1?scr[1]:g==2?scr[2]:scr[3])
                        : (g==0?scr[4]:g==1?scr[5]:g==2?scr[6]:scr[7]);
    int idx = nbrs[(((size_t)b*cR + r)*cN + n)*cK + k];
    int o = r*ROWS2 + b*N1 + idx;
    float sv = sng2[o];
    float sc = leaky(sc0 + sv + sSrel[r]);
    if (idx == 0) sc -= 1e9f;
    float mx = sc;
    mx = fmaxf(mx, __shfl_xor(mx,1,64)); mx = fmaxf(mx, __shfl_xor(mx,2,64));
    mx = fmaxf(mx, __shfl_xor(mx,4,64)); mx = fmaxf(mx, __shfl_xor(mx,8,64));
    float ex = __expf(sc - mx);
    float sm = ex;
    sm += __shfl_xor(sm,1,64); sm += __shfl_xor(sm,2,64);
    sm += __shfl_xor(sm,4,64); sm += __shfl_xor(sm,8,64);
    sAtt[wave][r][k] = ex/sm;
    sOff[wave][r][k] = o;
  }
  __syncthreads();

  float facc[8];
  #pragma unroll
  for (int r=0; r<8; ++r){
    float a0=0.f, a1=0.f;
    #pragma unroll
    for (int kk=0; kk<cK; kk+=2){
      float w0 = sAtt[wave][r][kk],   w1 = sAtt[wave][r][kk+1];
      int   o0 = sOff[wave][r][kk],   o1 = sOff[wave][r][kk+1];
      a0 += w0 * bfu(actb[(size_t)o0*cD + lane]);
      a1 += w1 * bfu(actb[(size_t)o1*cD + lane]);
    }
    facc[r] = a0 + a1;
  }

  const float rcur = rattW[lane], rrep = rattW[cD + lane];
  const float rb   = rattb[0];
  const float c0 = wsumall(cur * rcur);
  float rs[8];
  #pragma unroll
  for (int r=0; r<8; ++r) rs[r] = leaky(c0 + wsumall(facc[r]*rrep) + sRremb[r] + rb);
  float mx = rs[0];
  #pragma unroll
  for (int r=1; r<8; ++r) mx = fmaxf(mx, rs[r]);
  float es = 0.f; float ratt[8];
  #pragma unroll
  for (int r=0; r<8; ++r){ ratt[r] = __expf(rs[r]-mx); es += ratt[r]; }
  float inv = 1.f/es;
  float agg = 0.f;
  #pragma unroll
  for (int r=0; r<8; ++r) agg += (ratt[r]*inv) * facc[r];
  const float upd = cur + agg;

  float l0 = wsumall(upd * predW[lane*3 + 0]);
  float l1 = wsumall(upd * predW[lane*3 + 1]);
  float l2 = wsumall(upd * predW[lane*3 + 2]);
  if (lane == 0){
    l0 += predb[0]; l1 += predb[1]; l2 += predb[2];
    float m2 = fmaxf(l0, fmaxf(l1, l2));
    float e0 = __expf(l0-m2), e1 = __expf(l1-m2), e2 = __expf(l2-m2);
    float is = 1.f/(e0+e1+e2);
    out[(size_t)gn*3+0] = e0*is;
    out[(size_t)gn*3+1] = e1*is;
    out[(size_t)gn*3+2] = e2*is;
  }
}

// ================================ launch =================================
extern "C" void kernel_launch(void* const* d_in, const int* in_sizes, int n_in,
                              void* d_out, int out_size, void* d_ws, size_t ws_size,
                              hipStream_t stream)
{
  const float* X      = (const float*)d_in[0];
  const int*   nbrs   = (const int*)  d_in[1];
  const float* gW     = (const float*)d_in[2];
  const float* gU     = (const float*)d_in[3];
  const float* gb     = (const float*)d_in[4];
  const float* relemb = (const float*)d_in[5];
  const float* pW     = (const float*)d_in[6];
  const float* pb     = (const float*)d_in[7];
  const float* sattW  = (const float*)d_in[8];
  const float* sattb  = (const float*)d_in[9];
  const float* rattW  = (const float*)d_in[10];
  const float* rattb  = (const float*)d_in[11];
  const float* predW  = (const float*)d_in[12];
  const float* predb  = (const float*)d_in[13];
  float* out = (float*)d_out;

  // workspace: node fp32 | act bf16 (r-major) | sng fp32
  float*          node  = (float*)d_ws;                                 // NODES*cD
  unsigned short* actb  = (unsigned short*)(node + (size_t)NODES*cD);   // cR*ROWS2*cD bf16
  float*          sng2  = (float*)(actb + (size_t)cR*ROWS2*cD);         // cR*ROWS2

  k_gru <<<NODES/16, 256, 0, stream>>>(X, gW, gU, gb, pW, pb, sattW,
                                       node, actb, sng2);
  k_attn<<<NODES/4, 256, 0, stream>>>(node, nbrs, sattW, sattb, rattW, rattb,
                                      predW, predb, relemb, actb, sng2, out);
}